// Round 2
// baseline (8828.033 us; speedup 1.0000x reference)
//
#include <hip/hip_runtime.h>

#define NTOT 4096
#define NBATCH 4
#define KNN 20

constexpr float NEG_INF = -3.0e38f;

// ---------------- prep: fold BN scale into weights ----------------
// Wc rows [0,O): Wa*s  (applied to neighbor features -> U)
// Wc rows [O,2O): (Wb-Wa)*s (applied to center features -> V)
// bias[o] = b - m*s  (added to V half in GEMM epilogue)
__global__ void prep_w(const float* __restrict__ W, const float* __restrict__ gg,
                       const float* __restrict__ bb, const float* __restrict__ mm,
                       const float* __restrict__ vv, float* __restrict__ Wc,
                       float* __restrict__ bias, int O, int C) {
  int t = blockIdx.x * 256 + threadIdx.x;
  if (t >= 2 * O * C) return;
  int o2 = t / C, c = t - o2 * C;
  int o = (o2 < O) ? o2 : o2 - O;
  float s = gg[o] * rsqrtf(vv[o] + 1e-5f);
  float w = (o2 < O) ? W[o * 2 * C + c] * s
                     : (W[o * 2 * C + C + c] - W[o * 2 * C + c]) * s;
  Wc[o2 * C + c] = w;
  if (o2 >= O && c == 0) bias[o] = bb[o] - mm[o] * s;
}

// ---------------- fused distance + top-20 KNN ----------------
// block = 256 threads = 32 rows x 8 threads/row. Each thread keeps a private
// top-20 (replace-min) over its 512-column subset; merge 8x20 per row at end.
// Ranking key: -||xi - xj||^2 computed DIRECTLY (sub then square-accumulate).
// This avoids the catastrophic cancellation of 2*dot - |xi|^2 - |xj|^2 and
// matches the float64 arbiter's ordering far better (boundary-flip fix).
template <int C>
__global__ void knn_k(const float* __restrict__ feat, int* __restrict__ outidx) {
  constexpr int S = (C == 3) ? 4 : (C + 4);  // pad: breaks LDS bank aliasing
  __shared__ __align__(16) float sA[64 * S];
  __shared__ float mval[32 * 8 * KNN];
  __shared__ int midx[32 * 8 * KNN];

  int tid = threadIdx.x;
  int rb = blockIdx.x & 127;  // 4096/32 = 128 row-blocks per batch
  int b = blockIdx.x >> 7;
  int row0 = rb * 32;
  int r = tid >> 3, q = tid & 7;
  int i = row0 + r;
  const float* fb = feat + (size_t)b * NTOT * C;

  float cf[C];
  if (C % 4 == 0) {
#pragma unroll
    for (int c4 = 0; c4 < C / 4; c4++)
      *(float4*)&cf[c4 * 4] = *(const float4*)&fb[(size_t)i * C + c4 * 4];
  } else {
#pragma unroll
    for (int c = 0; c < C; c++) cf[c] = fb[(size_t)i * C + c];
  }

  float tv[KNN];
  int tj[KNN];
#pragma unroll
  for (int t = 0; t < KNN; t++) {
    tv[t] = NEG_INF;
    tj[t] = 0;
  }
  float minv = NEG_INF;
  int minp = 0;

  for (int jt = 0; jt < NTOT; jt += 64) {
    __syncthreads();
    if (C == 3) {
      if (tid < 64) {
        sA[tid * S + 0] = fb[(size_t)(jt + tid) * 3 + 0];
        sA[tid * S + 1] = fb[(size_t)(jt + tid) * 3 + 1];
        sA[tid * S + 2] = fb[(size_t)(jt + tid) * 3 + 2];
      }
    } else {
      constexpr int NV = 64 * C / 4;  // float4 count
#pragma unroll
      for (int l = 0; l < NV / 256; l++) {
        int e = tid + 256 * l;
        int rr = e / (C / 4), c4 = e % (C / 4);
        float4 v = *(const float4*)&fb[(size_t)(jt + rr) * C + c4 * 4];
        *(float4*)&sA[rr * S + c4 * 4] = v;
      }
    }
    __syncthreads();

    for (int cc = 0; cc < 8; cc++) {
      int jl = cc * 8 + q;
      int j = jt + jl;
      float val;
      if (C == 3) {
        float d0 = cf[0] - sA[jl * S];
        float d1 = cf[1] - sA[jl * S + 1];
        float d2 = cf[2] - sA[jl * S + 2];
        val = -(d0 * d0 + d1 * d1 + d2 * d2);
      } else {
        float a0 = 0.f, a1 = 0.f, a2 = 0.f, a3 = 0.f;
#pragma unroll
        for (int c4 = 0; c4 < C / 4; c4++) {
          float4 v = *(const float4*)&sA[jl * S + c4 * 4];
          float d0 = cf[c4 * 4 + 0] - v.x;
          float d1 = cf[c4 * 4 + 1] - v.y;
          float d2 = cf[c4 * 4 + 2] - v.z;
          float d3 = cf[c4 * 4 + 3] - v.w;
          a0 = fmaf(d0, d0, a0);
          a1 = fmaf(d1, d1, a1);
          a2 = fmaf(d2, d2, a2);
          a3 = fmaf(d3, d3, a3);
        }
        val = -((a0 + a1) + (a2 + a3));
      }
      if (val > minv) {
#pragma unroll
        for (int t = 0; t < KNN; t++) {
          bool w = (minp == t);
          tv[t] = w ? val : tv[t];
          tj[t] = w ? j : tj[t];
        }
        minv = tv[0];
        minp = 0;
#pragma unroll
        for (int t = 1; t < KNN; t++)
          if (tv[t] < minv) {
            minv = tv[t];
            minp = t;
          }
      }
    }
  }

  __syncthreads();
#pragma unroll
  for (int t = 0; t < KNN; t++) {
    mval[(r * 8 + q) * KNN + t] = tv[t];
    midx[(r * 8 + q) * KNN + t] = tj[t];
  }
  __syncthreads();
  if (tid < 32) {
    int base = tid * 8 * KNN;
    int* op = outidx + ((size_t)b * NTOT + row0 + tid) * KNN;
    for (int t = 0; t < KNN; t++) {
      float best = NEG_INF;
      int bp = 0;
      for (int s2 = 0; s2 < 8 * KNN; s2++) {
        float v = mval[base + s2];
        if (v > best) {
          best = v;
          bp = s2;
        }
      }
      op[t] = midx[base + bp];
      mval[base + bp] = NEG_INF;
    }
  }
}

// ---------------- GEMM: Y[M x N2] = A[M x K] * Wc[N2 x K]^T (+bias on V half) --
__global__ __launch_bounds__(256) void gemm_k(const float* __restrict__ A,
                                              const float* __restrict__ Wc,
                                              const float* __restrict__ bias,
                                              float* __restrict__ Y, int K, int N2,
                                              int O) {
  __shared__ float As[8 * 68];
  __shared__ float Bs[8 * 68];
  int tid = threadIdx.x;
  int n0 = blockIdx.x * 64;
  int m0 = blockIdx.y * 64;
  int tx = tid & 15, ty = tid >> 4;
  float acc[4][4] = {};
  for (int k0 = 0; k0 < K; k0 += 8) {
    __syncthreads();
    {
      int e = tid, mm = e >> 3, kk = e & 7;
      As[kk * 68 + mm] = (k0 + kk < K) ? A[(size_t)(m0 + mm) * K + k0 + kk] : 0.f;
      int nn = mm;
      Bs[kk * 68 + nn] = (k0 + kk < K) ? Wc[(size_t)(n0 + nn) * K + k0 + kk] : 0.f;
      e = tid + 256;
      mm = e >> 3;
      kk = e & 7;
      As[kk * 68 + mm] = (k0 + kk < K) ? A[(size_t)(m0 + mm) * K + k0 + kk] : 0.f;
      nn = mm;
      Bs[kk * 68 + nn] = (k0 + kk < K) ? Wc[(size_t)(n0 + nn) * K + k0 + kk] : 0.f;
    }
    __syncthreads();
#pragma unroll
    for (int kk = 0; kk < 8; kk++) {
      float4 av = *(float4*)&As[kk * 68 + ty * 4];
      float4 bv = *(float4*)&Bs[kk * 68 + tx * 4];
      float a[4] = {av.x, av.y, av.z, av.w};
      float bb2[4] = {bv.x, bv.y, bv.z, bv.w};
#pragma unroll
      for (int ii = 0; ii < 4; ii++)
#pragma unroll
        for (int jj = 0; jj < 4; jj++) acc[ii][jj] += a[ii] * bb2[jj];
    }
  }
  int col = n0 + tx * 4;
  bool isV = (col >= O);  // O % 64 == 0 -> whole 4-group same side
  float b0 = 0.f, b1 = 0.f, b2 = 0.f, b3 = 0.f;
  if (isV) {
    b0 = bias[col + 0 - O];
    b1 = bias[col + 1 - O];
    b2 = bias[col + 2 - O];
    b3 = bias[col + 3 - O];
  }
#pragma unroll
  for (int ii = 0; ii < 4; ii++) {
    int row = m0 + ty * 4 + ii;
    float4 o4;
    o4.x = acc[ii][0] + b0;
    o4.y = acc[ii][1] + b1;
    o4.z = acc[ii][2] + b2;
    o4.w = acc[ii][3] + b3;
    *(float4*)&Y[(size_t)row * N2 + col] = o4;
  }
}

// ---------------- gather + max + LeakyReLU ----------------
__global__ void gmax_k(const float* __restrict__ Y, const int* __restrict__ idx,
                       float* __restrict__ out, int O) {
  int p = blockIdx.x;  // global point 0..16383
  int o = threadIdx.x; // 0..O-1
  int b = p >> 12;
  int N2 = 2 * O;
  const int* ip = idx + (size_t)p * KNN;
  float m = NEG_INF;
#pragma unroll
  for (int k = 0; k < KNN; k++) {
    int j = ip[k];
    m = fmaxf(m, Y[((size_t)(b * NTOT + j)) * N2 + o]);
  }
  float val = Y[(size_t)p * N2 + O + o] + m;
  out[(size_t)p * O + o] = (val >= 0.f) ? val : 0.2f * val;
}

// ---------------- host side ----------------
template <int C, int O>
static void run_layer(const float* fin, void* const* w5, float* fout, float* Wc,
                      float* biasb, int* idx, float* Y, hipStream_t stream) {
  const float* W = (const float*)w5[0];
  const float* g = (const float*)w5[1];
  const float* bb = (const float*)w5[2];
  const float* mm = (const float*)w5[3];
  const float* vv = (const float*)w5[4];
  int N2 = 2 * O;
  prep_w<<<(2 * O * C + 255) / 256, 256, 0, stream>>>(W, g, bb, mm, vv, Wc, biasb, O, C);
  knn_k<C><<<NBATCH * (NTOT / 32), 256, 0, stream>>>(fin, idx);
  dim3 gg(N2 / 64, NBATCH * NTOT / 64);
  gemm_k<<<gg, 256, 0, stream>>>(fin, Wc, biasb, Y, C, N2, O);
  gmax_k<<<NBATCH * NTOT, O, 0, stream>>>(Y, idx, fout, O);
}

extern "C" void kernel_launch(void* const* d_in, const int* in_sizes, int n_in,
                              void* d_out, int out_size, void* d_ws, size_t ws_size,
                              hipStream_t stream) {
  const float* x = (const float*)d_in[0];
  char* ws = (char*)d_ws;
  // offsets (256B aligned)
  float* Wc = (float*)(ws + 0);            // 512*128*4 = 262144
  float* biasb = (float*)(ws + 262144);    // 1024
  int* idx = (int*)(ws + 263168);          // 16384*20*4 = 1310720
  float* Y = (float*)(ws + 1573888);       // 16384*512*4 = 33554432
  float* x1 = (float*)(ws + 35128320);     // 16384*64*4 = 4194304
  float* x2 = (float*)(ws + 39322624);     // 4194304
  float* x3 = (float*)(ws + 43516928);     // 16384*128*4 = 8388608

  float* outf = (float*)d_out;

  run_layer<3, 64>(x, d_in + 1, x1, Wc, biasb, idx, Y, stream);
  run_layer<64, 64>(x1, d_in + 6, x2, Wc, biasb, idx, Y, stream);
  run_layer<64, 128>(x2, d_in + 11, x3, Wc, biasb, idx, Y, stream);
  run_layer<128, 256>(x3, d_in + 16, outf, Wc, biasb, idx, Y, stream);
}

// Round 3
// 3749.330 us; speedup vs baseline: 2.3546x; 2.3546x over previous
//
#include <hip/hip_runtime.h>

#define NTOT 4096
#define NBATCH 4
#define KNN 20

constexpr float NEG_INF = -3.0e38f;

// ---------------- prep: fold BN scale into weights ----------------
__global__ void prep_w(const float* __restrict__ W, const float* __restrict__ gg,
                       const float* __restrict__ bb, const float* __restrict__ mm,
                       const float* __restrict__ vv, float* __restrict__ Wc,
                       float* __restrict__ bias, int O, int C) {
  int t = blockIdx.x * 256 + threadIdx.x;
  if (t >= 2 * O * C) return;
  int o2 = t / C, c = t - o2 * C;
  int o = (o2 < O) ? o2 : o2 - O;
  float s = gg[o] * rsqrtf(vv[o] + 1e-5f);
  float w = (o2 < O) ? W[o * 2 * C + c] * s
                     : (W[o * 2 * C + C + c] - W[o * 2 * C + c]) * s;
  Wc[o2 * C + c] = w;
  if (o2 >= O && c == 0) bias[o] = bb[o] - mm[o] * s;
}

// ---------------- KNN for C=3 (registers fit; keep R2 structure) ----------
__global__ __launch_bounds__(256, 2) void knn3_k(const float* __restrict__ feat,
                                                 int* __restrict__ outidx) {
  __shared__ __align__(16) float sA[64 * 4];
  __shared__ float mval[32 * 8 * KNN];
  __shared__ int midx[32 * 8 * KNN];

  int tid = threadIdx.x;
  int rb = blockIdx.x & 127;
  int b = blockIdx.x >> 7;
  int row0 = rb * 32;
  int r = tid >> 3, q = tid & 7;
  int i = row0 + r;
  const float* fb = feat + (size_t)b * NTOT * 3;

  float c0 = fb[(size_t)i * 3 + 0];
  float c1 = fb[(size_t)i * 3 + 1];
  float c2 = fb[(size_t)i * 3 + 2];

  float tv[KNN];
  int tj[KNN];
#pragma unroll
  for (int t = 0; t < KNN; t++) { tv[t] = NEG_INF; tj[t] = 0; }
  float minv = NEG_INF;
  int minp = 0;

  for (int jt = 0; jt < NTOT; jt += 64) {
    __syncthreads();
    if (tid < 64) {
      sA[tid * 4 + 0] = fb[(size_t)(jt + tid) * 3 + 0];
      sA[tid * 4 + 1] = fb[(size_t)(jt + tid) * 3 + 1];
      sA[tid * 4 + 2] = fb[(size_t)(jt + tid) * 3 + 2];
    }
    __syncthreads();

    for (int cc = 0; cc < 8; cc++) {
      int jl = cc * 8 + q;
      int j = jt + jl;
      float d0 = c0 - sA[jl * 4];
      float d1 = c1 - sA[jl * 4 + 1];
      float d2 = c2 - sA[jl * 4 + 2];
      float val = -(d0 * d0 + d1 * d1 + d2 * d2);
      if (val > minv) {
#pragma unroll
        for (int t = 0; t < KNN; t++) {
          bool w = (minp == t);
          tv[t] = w ? val : tv[t];
          tj[t] = w ? j : tj[t];
        }
        minv = tv[0];
        minp = 0;
#pragma unroll
        for (int t = 1; t < KNN; t++)
          if (tv[t] < minv) { minv = tv[t]; minp = t; }
      }
    }
  }

  __syncthreads();
#pragma unroll
  for (int t = 0; t < KNN; t++) {
    mval[(r * 8 + q) * KNN + t] = tv[t];
    midx[(r * 8 + q) * KNN + t] = tj[t];
  }
  __syncthreads();
  if (tid < 32) {
    int base = tid * 8 * KNN;
    int* op = outidx + ((size_t)b * NTOT + row0 + tid) * KNN;
    for (int t = 0; t < KNN; t++) {
      float best = NEG_INF;
      int bp = 0;
      for (int s2 = 0; s2 < 8 * KNN; s2++) {
        float v = mval[base + s2];
        if (v > best) { best = v; bp = s2; }
      }
      op[t] = midx[base + bp];
      mval[base + bp] = NEG_INF;
    }
  }
}

// ---------------- GEMM-tiled KNN for C in {64,128} ----------------
// Block computes a 64(i) x 64(j) distance tile with 4x4 register blocking.
// No per-thread feature vector -> no scratch spill (R2's 19 GB FETCH bug).
template <int C>
__global__ __launch_bounds__(256, 1) void knn_g(const float* __restrict__ feat,
                                                int* __restrict__ outidx) {
  constexpr int P = C + 2;  // row pad: float2 reads stay 8B-aligned, b-frag 4-way max
  __shared__ __align__(16) float At[64 * P];
  __shared__ __align__(16) float Bt[64 * P];
  __shared__ __align__(16) float Dt[64 * 68];

  int tid = threadIdx.x;
  int b = blockIdx.x >> 6;
  int it = blockIdx.x & 63;
  int i0 = it * 64;
  const float* fb = feat + (size_t)b * NTOT * C;

  constexpr int F4R = C / 4;       // float4 per feature row
  constexpr int NF4 = 64 * F4R;    // float4 per 64-row tile

  // stage A tile once (row-major, coalesced global, scalar LDS stores)
#pragma unroll
  for (int l = 0; l < NF4 / 256; l++) {
    int e = tid + 256 * l;
    int rr = e / F4R, c4 = e % F4R;
    float4 v = *(const float4*)&fb[(size_t)(i0 + rr) * C + c4 * 4];
    At[rr * P + c4 * 4 + 0] = v.x;
    At[rr * P + c4 * 4 + 1] = v.y;
    At[rr * P + c4 * 4 + 2] = v.z;
    At[rr * P + c4 * 4 + 3] = v.w;
  }

  int tx = tid & 15, ty = tid >> 4;  // compute mapping: 16x16 threads, 4x4 each
  int r = tid >> 2, s = tid & 3;     // selection mapping: 64 rows x 4 lanes

  float tv[KNN];
  int tj[KNN];
#pragma unroll
  for (int t = 0; t < KNN; t++) { tv[t] = NEG_INF; tj[t] = 0; }
  float minv = NEG_INF;
  int minp = 0;

  for (int jt = 0; jt < 64; jt++) {
    int j0 = jt * 64;
    __syncthreads();  // prev select done (Dt), prev compute done (Bt)
#pragma unroll
    for (int l = 0; l < NF4 / 256; l++) {
      int e = tid + 256 * l;
      int rr = e / F4R, c4 = e % F4R;
      float4 v = *(const float4*)&fb[(size_t)(j0 + rr) * C + c4 * 4];
      Bt[rr * P + c4 * 4 + 0] = v.x;
      Bt[rr * P + c4 * 4 + 1] = v.y;
      Bt[rr * P + c4 * 4 + 2] = v.z;
      Bt[rr * P + c4 * 4 + 3] = v.w;
    }
    __syncthreads();

    float acc[4][4] = {};
#pragma unroll 8
    for (int kk = 0; kk < C; kk += 2) {
      float2 a0 = *(const float2*)&At[(ty * 4 + 0) * P + kk];
      float2 a1 = *(const float2*)&At[(ty * 4 + 1) * P + kk];
      float2 a2 = *(const float2*)&At[(ty * 4 + 2) * P + kk];
      float2 a3 = *(const float2*)&At[(ty * 4 + 3) * P + kk];
      float2 b0 = *(const float2*)&Bt[(tx * 4 + 0) * P + kk];
      float2 b1 = *(const float2*)&Bt[(tx * 4 + 1) * P + kk];
      float2 b2 = *(const float2*)&Bt[(tx * 4 + 2) * P + kk];
      float2 b3 = *(const float2*)&Bt[(tx * 4 + 3) * P + kk];
      float2 av[4] = {a0, a1, a2, a3};
      float2 bv[4] = {b0, b1, b2, b3};
#pragma unroll
      for (int ii = 0; ii < 4; ii++)
#pragma unroll
        for (int jj = 0; jj < 4; jj++) {
          float dx = av[ii].x - bv[jj].x;
          acc[ii][jj] = fmaf(dx, dx, acc[ii][jj]);
          float dy = av[ii].y - bv[jj].y;
          acc[ii][jj] = fmaf(dy, dy, acc[ii][jj]);
        }
    }

#pragma unroll
    for (int ii = 0; ii < 4; ii++) {
      float4 o4;
      o4.x = -acc[ii][0];
      o4.y = -acc[ii][1];
      o4.z = -acc[ii][2];
      o4.w = -acc[ii][3];
      *(float4*)&Dt[(ty * 4 + ii) * 68 + tx * 4] = o4;
    }
    __syncthreads();

    // selection: 4 lanes per row scan 16 candidates each
#pragma unroll
    for (int t = 0; t < 16; t++) {
      float val = Dt[r * 68 + s * 16 + t];
      int j = j0 + s * 16 + t;
      if (val > minv) {
#pragma unroll
        for (int u = 0; u < KNN; u++) {
          bool w = (minp == u);
          tv[u] = w ? val : tv[u];
          tj[u] = w ? j : tj[u];
        }
        minv = tv[0];
        minp = 0;
#pragma unroll
        for (int u = 1; u < KNN; u++)
          if (tv[u] < minv) { minv = tv[u]; minp = u; }
      }
    }
  }

  // merge the 4 lanes of each row via width-4 shuffles (lanes are contiguous)
  int* op = outidx + ((size_t)b * NTOT + i0 + r) * KNN;
#pragma unroll 1
  for (int t = 0; t < KNN; t++) {
    float bv = tv[0];
    int bp = 0;
#pragma unroll
    for (int u = 1; u < KNN; u++)
      if (tv[u] > bv) { bv = tv[u]; bp = u; }
    float wv = bv;
    int wl = s;
#pragma unroll
    for (int m = 1; m < 4; m <<= 1) {
      float ov = __shfl_xor(wv, m, 4);
      int ol = __shfl_xor(wl, m, 4);
      if (ov > wv || (ov == wv && ol < wl)) { wv = ov; wl = ol; }
    }
    if (wl == s) {
      int myj = 0;
#pragma unroll
      for (int u = 0; u < KNN; u++)
        if (u == bp) myj = tj[u];
      op[t] = myj;
#pragma unroll
      for (int u = 0; u < KNN; u++)
        if (u == bp) tv[u] = NEG_INF;
    }
  }
}

// ---------------- GEMM: Y[M x N2] = A[M x K] * Wc[N2 x K]^T (+bias on V half) --
__global__ __launch_bounds__(256) void gemm_k(const float* __restrict__ A,
                                              const float* __restrict__ Wc,
                                              const float* __restrict__ bias,
                                              float* __restrict__ Y, int K, int N2,
                                              int O) {
  __shared__ float As[8 * 68];
  __shared__ float Bs[8 * 68];
  int tid = threadIdx.x;
  int n0 = blockIdx.x * 64;
  int m0 = blockIdx.y * 64;
  int tx = tid & 15, ty = tid >> 4;
  float acc[4][4] = {};
  for (int k0 = 0; k0 < K; k0 += 8) {
    __syncthreads();
    {
      int e = tid, mm = e >> 3, kk = e & 7;
      As[kk * 68 + mm] = (k0 + kk < K) ? A[(size_t)(m0 + mm) * K + k0 + kk] : 0.f;
      int nn = mm;
      Bs[kk * 68 + nn] = (k0 + kk < K) ? Wc[(size_t)(n0 + nn) * K + k0 + kk] : 0.f;
      e = tid + 256;
      mm = e >> 3;
      kk = e & 7;
      As[kk * 68 + mm] = (k0 + kk < K) ? A[(size_t)(m0 + mm) * K + k0 + kk] : 0.f;
      nn = mm;
      Bs[kk * 68 + nn] = (k0 + kk < K) ? Wc[(size_t)(n0 + nn) * K + k0 + kk] : 0.f;
    }
    __syncthreads();
#pragma unroll
    for (int kk = 0; kk < 8; kk++) {
      float4 av = *(float4*)&As[kk * 68 + ty * 4];
      float4 bv = *(float4*)&Bs[kk * 68 + tx * 4];
      float a[4] = {av.x, av.y, av.z, av.w};
      float bb2[4] = {bv.x, bv.y, bv.z, bv.w};
#pragma unroll
      for (int ii = 0; ii < 4; ii++)
#pragma unroll
        for (int jj = 0; jj < 4; jj++) acc[ii][jj] += a[ii] * bb2[jj];
    }
  }
  int col = n0 + tx * 4;
  bool isV = (col >= O);
  float b0 = 0.f, b1 = 0.f, b2 = 0.f, b3 = 0.f;
  if (isV) {
    b0 = bias[col + 0 - O];
    b1 = bias[col + 1 - O];
    b2 = bias[col + 2 - O];
    b3 = bias[col + 3 - O];
  }
#pragma unroll
  for (int ii = 0; ii < 4; ii++) {
    int row = m0 + ty * 4 + ii;
    float4 o4;
    o4.x = acc[ii][0] + b0;
    o4.y = acc[ii][1] + b1;
    o4.z = acc[ii][2] + b2;
    o4.w = acc[ii][3] + b3;
    *(float4*)&Y[(size_t)row * N2 + col] = o4;
  }
}

// ---------------- gather + max + LeakyReLU ----------------
__global__ void gmax_k(const float* __restrict__ Y, const int* __restrict__ idx,
                       float* __restrict__ out, int O) {
  int p = blockIdx.x;
  int o = threadIdx.x;
  int b = p >> 12;
  int N2 = 2 * O;
  const int* ip = idx + (size_t)p * KNN;
  float m = NEG_INF;
#pragma unroll
  for (int k = 0; k < KNN; k++) {
    int j = ip[k];
    m = fmaxf(m, Y[((size_t)(b * NTOT + j)) * N2 + o]);
  }
  float val = Y[(size_t)p * N2 + O + o] + m;
  out[(size_t)p * O + o] = (val >= 0.f) ? val : 0.2f * val;
}

// ---------------- host side ----------------
template <int C, int O>
static void run_layer(const float* fin, void* const* w5, float* fout, float* Wc,
                      float* biasb, int* idx, float* Y, hipStream_t stream) {
  const float* W = (const float*)w5[0];
  const float* g = (const float*)w5[1];
  const float* bb = (const float*)w5[2];
  const float* mm = (const float*)w5[3];
  const float* vv = (const float*)w5[4];
  int N2 = 2 * O;
  prep_w<<<(2 * O * C + 255) / 256, 256, 0, stream>>>(W, g, bb, mm, vv, Wc, biasb, O, C);
  if (C == 3) {
    knn3_k<<<NBATCH * (NTOT / 32), 256, 0, stream>>>(fin, idx);
  } else {
    knn_g<C == 3 ? 64 : C><<<NBATCH * (NTOT / 64), 256, 0, stream>>>(fin, idx);
  }
  dim3 gg(N2 / 64, NBATCH * NTOT / 64);
  gemm_k<<<gg, 256, 0, stream>>>(fin, Wc, biasb, Y, C, N2, O);
  gmax_k<<<NBATCH * NTOT, O, 0, stream>>>(Y, idx, fout, O);
}

extern "C" void kernel_launch(void* const* d_in, const int* in_sizes, int n_in,
                              void* d_out, int out_size, void* d_ws, size_t ws_size,
                              hipStream_t stream) {
  const float* x = (const float*)d_in[0];
  char* ws = (char*)d_ws;
  float* Wc = (float*)(ws + 0);            // 262144
  float* biasb = (float*)(ws + 262144);    // 1024
  int* idx = (int*)(ws + 263168);          // 1310720
  float* Y = (float*)(ws + 1573888);       // 33554432
  float* x1 = (float*)(ws + 35128320);     // 4194304
  float* x2 = (float*)(ws + 39322624);     // 4194304
  float* x3 = (float*)(ws + 43516928);     // 8388608

  float* outf = (float*)d_out;

  run_layer<3, 64>(x, d_in + 1, x1, Wc, biasb, idx, Y, stream);
  run_layer<64, 64>(x1, d_in + 6, x2, Wc, biasb, idx, Y, stream);
  run_layer<64, 128>(x2, d_in + 11, x3, Wc, biasb, idx, Y, stream);
  run_layer<128, 256>(x3, d_in + 16, outf, Wc, biasb, idx, Y, stream);
}

// Round 4
// 2208.512 us; speedup vs baseline: 3.9973x; 1.6977x over previous
//
#include <hip/hip_runtime.h>

#define NTOT 4096
#define NBATCH 4
#define KNN 20
#define JSPLIT 4

constexpr float NEG_INF = -3.0e38f;

__device__ __forceinline__ void topk_insert(float val, int j, float (&tv)[KNN],
                                            int (&tj)[KNN], float& minv, int& minp) {
  if (val > minv) {
#pragma unroll
    for (int u = 0; u < KNN; u++) {
      bool w = (minp == u);
      tv[u] = w ? val : tv[u];
      tj[u] = w ? j : tj[u];
    }
    minv = tv[0];
    minp = 0;
#pragma unroll
    for (int u = 1; u < KNN; u++)
      if (tv[u] < minv) { minv = tv[u]; minp = u; }
  }
}

// ---------------- prep: fold BN scale into weights ----------------
__global__ void prep_w(const float* __restrict__ W, const float* __restrict__ gg,
                       const float* __restrict__ bb, const float* __restrict__ mm,
                       const float* __restrict__ vv, float* __restrict__ Wc,
                       float* __restrict__ bias, int O, int C) {
  int t = blockIdx.x * 256 + threadIdx.x;
  if (t >= 2 * O * C) return;
  int o2 = t / C, c = t - o2 * C;
  int o = (o2 < O) ? o2 : o2 - O;
  float s = gg[o] * rsqrtf(vv[o] + 1e-5f);
  float w = (o2 < O) ? W[o * 2 * C + c] * s
                     : (W[o * 2 * C + C + c] - W[o * 2 * C + c]) * s;
  Wc[o2 * C + c] = w;
  if (o2 >= O && c == 0) bias[o] = bb[o] - mm[o] * s;
}

// ---------------- KNN for C=3 ----------
__global__ __launch_bounds__(256, 2) void knn3_k(const float* __restrict__ feat,
                                                 int* __restrict__ outidx) {
  __shared__ __align__(16) float sA[64 * 4];
  __shared__ float mval[32 * 8 * KNN];
  __shared__ int midx[32 * 8 * KNN];

  int tid = threadIdx.x;
  int rb = blockIdx.x & 127;
  int b = blockIdx.x >> 7;
  int row0 = rb * 32;
  int r = tid >> 3, q = tid & 7;
  int i = row0 + r;
  const float* fb = feat + (size_t)b * NTOT * 3;

  float c0 = fb[(size_t)i * 3 + 0];
  float c1 = fb[(size_t)i * 3 + 1];
  float c2 = fb[(size_t)i * 3 + 2];

  float tv[KNN];
  int tj[KNN];
#pragma unroll
  for (int t = 0; t < KNN; t++) { tv[t] = NEG_INF; tj[t] = 0; }
  float minv = NEG_INF;
  int minp = 0;

  for (int jt = 0; jt < NTOT; jt += 64) {
    __syncthreads();
    if (tid < 64) {
      sA[tid * 4 + 0] = fb[(size_t)(jt + tid) * 3 + 0];
      sA[tid * 4 + 1] = fb[(size_t)(jt + tid) * 3 + 1];
      sA[tid * 4 + 2] = fb[(size_t)(jt + tid) * 3 + 2];
    }
    __syncthreads();

    for (int cc = 0; cc < 8; cc++) {
      int jl = cc * 8 + q;
      int j = jt + jl;
      float d0 = c0 - sA[jl * 4];
      float d1 = c1 - sA[jl * 4 + 1];
      float d2 = c2 - sA[jl * 4 + 2];
      float val = -(d0 * d0 + d1 * d1 + d2 * d2);
      topk_insert(val, j, tv, tj, minv, minp);
    }
  }

  __syncthreads();
#pragma unroll
  for (int t = 0; t < KNN; t++) {
    mval[(r * 8 + q) * KNN + t] = tv[t];
    midx[(r * 8 + q) * KNN + t] = tj[t];
  }
  __syncthreads();
  if (tid < 32) {
    int base = tid * 8 * KNN;
    int* op = outidx + ((size_t)b * NTOT + row0 + tid) * KNN;
    for (int t = 0; t < KNN; t++) {
      float best = NEG_INF;
      int bp = 0;
      for (int s2 = 0; s2 < 8 * KNN; s2++) {
        float v = mval[base + s2];
        if (v > best) { best = v; bp = s2; }
      }
      op[t] = midx[base + bp];
      mval[base + bp] = NEG_INF;
    }
  }
}

// ---------------- GEMM-structured KNN for C in {64,128} ----------------
// 128(i) x 128(j) tile per block, 8x8 register block per thread, k-major LDS
// with bank swizzle. j-range split 4-ways across blocks (grid 512). Selection
// threads own a FIXED row (2 threads/row); distances bounce through Dt in two
// 64-col phases. Each selection thread dumps its top-20 as candidates; kmerge
// reduces 8x20 -> 20.
template <int C>
__global__ __launch_bounds__(256, 2) void knn_g(const float* __restrict__ feat,
                                                float* __restrict__ cval,
                                                int* __restrict__ cidx) {
  constexpr int P = 140;   // swizzled row: max col swz(127)=139
  constexpr int BK = 32;
  __shared__ float As[BK * P];
  __shared__ float Bs[BK * P];
  __shared__ float Dt[128 * 68];

  int tid = threadIdx.x;
  int js = blockIdx.x & (JSPLIT - 1);
  int it = (blockIdx.x >> 2) & 31;
  int b = blockIdx.x >> 7;
  int i0 = it * 128;
  const float* fb = feat + (size_t)b * NTOT * C;

  int tx = tid & 15, ty = tid >> 4;
  int aoff = (ty * 8) + (((ty * 8) >> 5) << 2);  // swz(ty*8)
  int boff = (tx * 8) + (((tx * 8) >> 5) << 2);  // swz(tx*8)
  int selr = tid >> 1;   // fixed row 0..127
  int sels = tid & 1;

  float tv[KNN];
  int tj[KNN];
#pragma unroll
  for (int t = 0; t < KNN; t++) { tv[t] = NEG_INF; tj[t] = 0; }
  float minv = NEG_INF;
  int minp = 0;

  for (int jt = 0; jt < NTOT / (128 * JSPLIT); jt++) {
    int j0 = js * (NTOT / JSPLIT) + jt * 128;
    float acc[8][8];
#pragma unroll
    for (int ii = 0; ii < 8; ii++)
#pragma unroll
      for (int jj = 0; jj < 8; jj++) acc[ii][jj] = 0.f;

    for (int kc = 0; kc < C; kc += BK) {
      __syncthreads();
#pragma unroll
      for (int l = 0; l < 4; l++) {
        int e = tid + 256 * l;          // float4 id: 128 rows x 8 f4-cols
        int rr = e >> 3, c4 = e & 7;
        int sc = rr + ((rr >> 5) << 2); // swz(row index)
        float4 va = *(const float4*)&fb[(size_t)(i0 + rr) * C + kc + c4 * 4];
        As[(c4 * 4 + 0) * P + sc] = va.x;
        As[(c4 * 4 + 1) * P + sc] = va.y;
        As[(c4 * 4 + 2) * P + sc] = va.z;
        As[(c4 * 4 + 3) * P + sc] = va.w;
        float4 vb = *(const float4*)&fb[(size_t)(j0 + rr) * C + kc + c4 * 4];
        Bs[(c4 * 4 + 0) * P + sc] = vb.x;
        Bs[(c4 * 4 + 1) * P + sc] = vb.y;
        Bs[(c4 * 4 + 2) * P + sc] = vb.z;
        Bs[(c4 * 4 + 3) * P + sc] = vb.w;
      }
      __syncthreads();
#pragma unroll 8
      for (int k = 0; k < BK; k++) {
        float4 a0 = *(const float4*)&As[k * P + aoff];
        float4 a1 = *(const float4*)&As[k * P + aoff + 4];
        float4 b0 = *(const float4*)&Bs[k * P + boff];
        float4 b1 = *(const float4*)&Bs[k * P + boff + 4];
        float av[8] = {a0.x, a0.y, a0.z, a0.w, a1.x, a1.y, a1.z, a1.w};
        float bv[8] = {b0.x, b0.y, b0.z, b0.w, b1.x, b1.y, b1.z, b1.w};
#pragma unroll
        for (int ii = 0; ii < 8; ii++)
#pragma unroll
          for (int jj = 0; jj < 8; jj++) {
            float d = av[ii] - bv[jj];
            acc[ii][jj] = fmaf(d, d, acc[ii][jj]);
          }
      }
    }

    // phase A: cols 0..63 of this j-tile
    if (tx < 8) {
#pragma unroll
      for (int ii = 0; ii < 8; ii++) {
        float4 o0 = make_float4(-acc[ii][0], -acc[ii][1], -acc[ii][2], -acc[ii][3]);
        float4 o1 = make_float4(-acc[ii][4], -acc[ii][5], -acc[ii][6], -acc[ii][7]);
        *(float4*)&Dt[(ty * 8 + ii) * 68 + tx * 8] = o0;
        *(float4*)&Dt[(ty * 8 + ii) * 68 + tx * 8 + 4] = o1;
      }
    }
    __syncthreads();
#pragma unroll
    for (int t4 = 0; t4 < 8; t4++) {
      float4 v = *(const float4*)&Dt[selr * 68 + sels * 32 + t4 * 4];
      int jb = j0 + sels * 32 + t4 * 4;
      topk_insert(v.x, jb + 0, tv, tj, minv, minp);
      topk_insert(v.y, jb + 1, tv, tj, minv, minp);
      topk_insert(v.z, jb + 2, tv, tj, minv, minp);
      topk_insert(v.w, jb + 3, tv, tj, minv, minp);
    }
    __syncthreads();
    // phase B: cols 64..127
    if (tx >= 8) {
#pragma unroll
      for (int ii = 0; ii < 8; ii++) {
        float4 o0 = make_float4(-acc[ii][0], -acc[ii][1], -acc[ii][2], -acc[ii][3]);
        float4 o1 = make_float4(-acc[ii][4], -acc[ii][5], -acc[ii][6], -acc[ii][7]);
        *(float4*)&Dt[(ty * 8 + ii) * 68 + (tx - 8) * 8] = o0;
        *(float4*)&Dt[(ty * 8 + ii) * 68 + (tx - 8) * 8 + 4] = o1;
      }
    }
    __syncthreads();
#pragma unroll
    for (int t4 = 0; t4 < 8; t4++) {
      float4 v = *(const float4*)&Dt[selr * 68 + sels * 32 + t4 * 4];
      int jb = j0 + 64 + sels * 32 + t4 * 4;
      topk_insert(v.x, jb + 0, tv, tj, minv, minp);
      topk_insert(v.y, jb + 1, tv, tj, minv, minp);
      topk_insert(v.z, jb + 2, tv, tj, minv, minp);
      topk_insert(v.w, jb + 3, tv, tj, minv, minp);
    }
    __syncthreads();
  }

  // dump candidates (transposed layout for coalesced merge reads)
  int p = b * NTOT + i0 + selr;
  int sub = js * 2 + sels;
#pragma unroll
  for (int t = 0; t < KNN; t++) {
    cval[(size_t)(sub * KNN + t) * (NBATCH * NTOT) + p] = tv[t];
    cidx[(size_t)(sub * KNN + t) * (NBATCH * NTOT) + p] = tj[t];
  }
}

// merge 8 sub-lists of 20 -> final top-20 indices per point
__global__ void kmerge(const float* __restrict__ cval, const int* __restrict__ cidx,
                       int* __restrict__ outidx) {
  int p = blockIdx.x * 256 + threadIdx.x;  // 0..16383
  float tv[KNN];
  int tj[KNN];
#pragma unroll
  for (int t = 0; t < KNN; t++) { tv[t] = NEG_INF; tj[t] = 0; }
  float minv = NEG_INF;
  int minp = 0;
  for (int t = 0; t < JSPLIT * 2 * KNN; t++) {
    float v = cval[(size_t)t * (NBATCH * NTOT) + p];
    int j = cidx[(size_t)t * (NBATCH * NTOT) + p];
    topk_insert(v, j, tv, tj, minv, minp);
  }
#pragma unroll
  for (int t = 0; t < KNN; t++) outidx[(size_t)p * KNN + t] = tj[t];
}

// ---------------- GEMM: Y[M x N2] = A[M x K] * Wc[N2 x K]^T (+bias on V half) --
__global__ __launch_bounds__(256) void gemm_k(const float* __restrict__ A,
                                              const float* __restrict__ Wc,
                                              const float* __restrict__ bias,
                                              float* __restrict__ Y, int K, int N2,
                                              int O) {
  __shared__ float As[8 * 68];
  __shared__ float Bs[8 * 68];
  int tid = threadIdx.x;
  int n0 = blockIdx.x * 64;
  int m0 = blockIdx.y * 64;
  int tx = tid & 15, ty = tid >> 4;
  float acc[4][4] = {};
  for (int k0 = 0; k0 < K; k0 += 8) {
    __syncthreads();
    {
      int e = tid, mm = e >> 3, kk = e & 7;
      As[kk * 68 + mm] = (k0 + kk < K) ? A[(size_t)(m0 + mm) * K + k0 + kk] : 0.f;
      int nn = mm;
      Bs[kk * 68 + nn] = (k0 + kk < K) ? Wc[(size_t)(n0 + nn) * K + k0 + kk] : 0.f;
      e = tid + 256;
      mm = e >> 3;
      kk = e & 7;
      As[kk * 68 + mm] = (k0 + kk < K) ? A[(size_t)(m0 + mm) * K + k0 + kk] : 0.f;
      nn = mm;
      Bs[kk * 68 + nn] = (k0 + kk < K) ? Wc[(size_t)(n0 + nn) * K + k0 + kk] : 0.f;
    }
    __syncthreads();
#pragma unroll
    for (int kk = 0; kk < 8; kk++) {
      float4 av = *(float4*)&As[kk * 68 + ty * 4];
      float4 bv = *(float4*)&Bs[kk * 68 + tx * 4];
      float a[4] = {av.x, av.y, av.z, av.w};
      float bb2[4] = {bv.x, bv.y, bv.z, bv.w};
#pragma unroll
      for (int ii = 0; ii < 4; ii++)
#pragma unroll
        for (int jj = 0; jj < 4; jj++) acc[ii][jj] += a[ii] * bb2[jj];
    }
  }
  int col = n0 + tx * 4;
  bool isV = (col >= O);
  float b0 = 0.f, b1 = 0.f, b2 = 0.f, b3 = 0.f;
  if (isV) {
    b0 = bias[col + 0 - O];
    b1 = bias[col + 1 - O];
    b2 = bias[col + 2 - O];
    b3 = bias[col + 3 - O];
  }
#pragma unroll
  for (int ii = 0; ii < 4; ii++) {
    int row = m0 + ty * 4 + ii;
    float4 o4;
    o4.x = acc[ii][0] + b0;
    o4.y = acc[ii][1] + b1;
    o4.z = acc[ii][2] + b2;
    o4.w = acc[ii][3] + b3;
    *(float4*)&Y[(size_t)row * N2 + col] = o4;
  }
}

// ---------------- gather + max + LeakyReLU ----------------
__global__ void gmax_k(const float* __restrict__ Y, const int* __restrict__ idx,
                       float* __restrict__ out, int O) {
  int p = blockIdx.x;
  int o = threadIdx.x;
  int b = p >> 12;
  int N2 = 2 * O;
  const int* ip = idx + (size_t)p * KNN;
  float m = NEG_INF;
#pragma unroll
  for (int k = 0; k < KNN; k++) {
    int j = ip[k];
    m = fmaxf(m, Y[((size_t)(b * NTOT + j)) * N2 + o]);
  }
  float val = Y[(size_t)p * N2 + O + o] + m;
  out[(size_t)p * O + o] = (val >= 0.f) ? val : 0.2f * val;
}

// ---------------- host side ----------------
template <int C, int O>
static void run_layer(const float* fin, void* const* w5, float* fout, float* Wc,
                      float* biasb, int* idx, float* Y, float* cval, int* cidx,
                      hipStream_t stream) {
  const float* W = (const float*)w5[0];
  const float* g = (const float*)w5[1];
  const float* bb = (const float*)w5[2];
  const float* mm = (const float*)w5[3];
  const float* vv = (const float*)w5[4];
  int N2 = 2 * O;
  prep_w<<<(2 * O * C + 255) / 256, 256, 0, stream>>>(W, g, bb, mm, vv, Wc, biasb, O, C);
  if (C == 3) {
    knn3_k<<<NBATCH * (NTOT / 32), 256, 0, stream>>>(fin, idx);
  } else {
    knn_g<C == 3 ? 64 : C><<<NBATCH * 32 * JSPLIT, 256, 0, stream>>>(fin, cval, cidx);
    kmerge<<<NBATCH * NTOT / 256, 256, 0, stream>>>(cval, cidx, idx);
  }
  dim3 gg(N2 / 64, NBATCH * NTOT / 64);
  gemm_k<<<gg, 256, 0, stream>>>(fin, Wc, biasb, Y, C, N2, O);
  gmax_k<<<NBATCH * NTOT, O, 0, stream>>>(Y, idx, fout, O);
}

extern "C" void kernel_launch(void* const* d_in, const int* in_sizes, int n_in,
                              void* d_out, int out_size, void* d_ws, size_t ws_size,
                              hipStream_t stream) {
  const float* x = (const float*)d_in[0];
  char* ws = (char*)d_ws;
  float* Wc = (float*)(ws + 0);            // 262144
  float* biasb = (float*)(ws + 262144);    // 1024
  int* idx = (int*)(ws + 263168);          // 1310720
  float* Y = (float*)(ws + 1573888);       // 33554432
  float* x1 = (float*)(ws + 35128320);     // 4194304
  float* x2 = (float*)(ws + 39322624);     // 4194304
  float* x3 = (float*)(ws + 43516928);     // 8388608

  // knn candidate scratch aliases Y (knn_g+kmerge finish before gemm_k writes Y)
  float* cval = Y;                              // 160*16384*4 = 10485760
  int* cidx = (int*)((char*)Y + 10485760);      // 10485760

  float* outf = (float*)d_out;

  run_layer<3, 64>(x, d_in + 1, x1, Wc, biasb, idx, Y, cval, cidx, stream);
  run_layer<64, 64>(x1, d_in + 6, x2, Wc, biasb, idx, Y, cval, cidx, stream);
  run_layer<64, 128>(x2, d_in + 11, x3, Wc, biasb, idx, Y, cval, cidx, stream);
  run_layer<128, 256>(x3, d_in + 16, outf, Wc, biasb, idx, Y, cval, cidx, stream);
}

// Round 5
// 1671.657 us; speedup vs baseline: 5.2810x; 1.3212x over previous
//
#include <hip/hip_runtime.h>

#define NTOT 4096
#define NBATCH 4
#define KNN 20
#define JSPLIT 4
#define KSUB 16
#define KMRG 28

constexpr float NEG_INF = -3.0e38f;

__device__ __forceinline__ unsigned pk(float f, int j) {
  unsigned u = __float_as_uint(f);
  u = (u & 0x80000000u) ? ~u : (u | 0x80000000u);
  return (u & 0xFFFFF000u) | (unsigned)j;
}

__device__ __forceinline__ void pins16(unsigned u, unsigned (&tv)[KSUB]) {
  if (u > tv[0]) {
    tv[0] = u;
#pragma unroll
    for (int x = 1; x < KSUB; x++) {
      unsigned mn = min(tv[0], tv[x]);
      unsigned mx = max(tv[0], tv[x]);
      tv[0] = mn;
      tv[x] = mx;
    }
  }
}

__device__ __forceinline__ void topk_insert(float val, int j, float (&tv)[KNN],
                                            int (&tj)[KNN], float& minv, int& minp) {
  if (val > minv) {
#pragma unroll
    for (int u = 0; u < KNN; u++) {
      bool w = (minp == u);
      tv[u] = w ? val : tv[u];
      tj[u] = w ? j : tj[u];
    }
    minv = tv[0];
    minp = 0;
#pragma unroll
    for (int u = 1; u < KNN; u++)
      if (tv[u] < minv) { minv = tv[u]; minp = u; }
  }
}

// ---------------- prep: fold BN scale into weights ----------------
__global__ void prep_w(const float* __restrict__ W, const float* __restrict__ gg,
                       const float* __restrict__ bb, const float* __restrict__ mm,
                       const float* __restrict__ vv, float* __restrict__ Wc,
                       float* __restrict__ bias, int O, int C) {
  int t = blockIdx.x * 256 + threadIdx.x;
  if (t >= 2 * O * C) return;
  int o2 = t / C, c = t - o2 * C;
  int o = (o2 < O) ? o2 : o2 - O;
  float s = gg[o] * rsqrtf(vv[o] + 1e-5f);
  float w = (o2 < O) ? W[o * 2 * C + c] * s
                     : (W[o * 2 * C + C + c] - W[o * 2 * C + c]) * s;
  Wc[o2 * C + c] = w;
  if (o2 >= O && c == 0) bias[o] = bb[o] - mm[o] * s;
}

// ---------------- half squared norms ----------------
template <int C>
__global__ void sqh_k(const float* __restrict__ f, float* __restrict__ sqh) {
  int p = blockIdx.x * 256 + threadIdx.x;
  const float* r = f + (size_t)p * C;
  float s = 0.f;
#pragma unroll
  for (int c4 = 0; c4 < C / 4; c4++) {
    float4 v = *(const float4*)&r[c4 * 4];
    s += v.x * v.x + v.y * v.y + v.z * v.z + v.w * v.w;
  }
  sqh[p] = 0.5f * s;
}

// ---------------- KNN for C=3 (exact) ----------
__global__ __launch_bounds__(256, 2) void knn3_k(const float* __restrict__ feat,
                                                 int* __restrict__ outidx) {
  __shared__ __align__(16) float sA[64 * 4];
  __shared__ float mval[32 * 8 * KNN];
  __shared__ int midx[32 * 8 * KNN];

  int tid = threadIdx.x;
  int rb = blockIdx.x & 127;
  int b = blockIdx.x >> 7;
  int row0 = rb * 32;
  int r = tid >> 3, q = tid & 7;
  int i = row0 + r;
  const float* fb = feat + (size_t)b * NTOT * 3;

  float c0 = fb[(size_t)i * 3 + 0];
  float c1 = fb[(size_t)i * 3 + 1];
  float c2 = fb[(size_t)i * 3 + 2];

  float tv[KNN];
  int tj[KNN];
#pragma unroll
  for (int t = 0; t < KNN; t++) { tv[t] = NEG_INF; tj[t] = 0; }
  float minv = NEG_INF;
  int minp = 0;

  for (int jt = 0; jt < NTOT; jt += 64) {
    __syncthreads();
    if (tid < 64) {
      sA[tid * 4 + 0] = fb[(size_t)(jt + tid) * 3 + 0];
      sA[tid * 4 + 1] = fb[(size_t)(jt + tid) * 3 + 1];
      sA[tid * 4 + 2] = fb[(size_t)(jt + tid) * 3 + 2];
    }
    __syncthreads();

    for (int cc = 0; cc < 8; cc++) {
      int jl = cc * 8 + q;
      int j = jt + jl;
      float d0 = c0 - sA[jl * 4];
      float d1 = c1 - sA[jl * 4 + 1];
      float d2 = c2 - sA[jl * 4 + 2];
      float val = -(d0 * d0 + d1 * d1 + d2 * d2);
      topk_insert(val, j, tv, tj, minv, minp);
    }
  }

  __syncthreads();
#pragma unroll
  for (int t = 0; t < KNN; t++) {
    mval[(r * 8 + q) * KNN + t] = tv[t];
    midx[(r * 8 + q) * KNN + t] = tj[t];
  }
  __syncthreads();
  if (tid < 32) {
    int base = tid * 8 * KNN;
    int* op = outidx + ((size_t)b * NTOT + row0 + tid) * KNN;
    for (int t = 0; t < KNN; t++) {
      float best = NEG_INF;
      int bp = 0;
      for (int s2 = 0; s2 < 8 * KNN; s2++) {
        float v = mval[base + s2];
        if (v > best) { best = v; bp = s2; }
      }
      op[t] = midx[base + bp];
      mval[base + bp] = NEG_INF;
    }
  }
}

// ---------------- KNN stage 1: dot-form distance + packed top-16 ----------
template <int C>
__global__ __launch_bounds__(256, 2) void knn_g(const float* __restrict__ feat,
                                                const float* __restrict__ sqh,
                                                unsigned* __restrict__ cval) {
  constexpr int P = 140;
  constexpr int BK = 32;
  __shared__ float As[BK * P];
  __shared__ float Bs[BK * P];
  __shared__ float Dt[128 * 68];
  __shared__ float sqB[128];

  int tid = threadIdx.x;
  int js = blockIdx.x & (JSPLIT - 1);
  int it = (blockIdx.x >> 2) & 31;
  int b = blockIdx.x >> 7;
  int i0 = it * 128;
  const float* fb = feat + (size_t)b * NTOT * C;

  int tx = tid & 15, ty = tid >> 4;
  int aoff = (ty * 8) + (((ty * 8) >> 5) << 2);
  int boff = (tx * 8) + (((tx * 8) >> 5) << 2);
  int selr = tid >> 1;
  int sels = tid & 1;

  unsigned tv[KSUB];
#pragma unroll
  for (int t = 0; t < KSUB; t++) tv[t] = 0u;

  for (int jt = 0; jt < NTOT / (128 * JSPLIT); jt++) {
    int j0 = js * (NTOT / JSPLIT) + jt * 128;
    if (tid < 128) sqB[tid] = sqh[b * NTOT + j0 + tid];

    float acc[8][8];
#pragma unroll
    for (int ii = 0; ii < 8; ii++)
#pragma unroll
      for (int jj = 0; jj < 8; jj++) acc[ii][jj] = 0.f;

    for (int kc = 0; kc < C; kc += BK) {
      __syncthreads();
#pragma unroll
      for (int l = 0; l < 4; l++) {
        int e = tid + 256 * l;
        int rr = e >> 3, c4 = e & 7;
        int sc = rr + ((rr >> 5) << 2);
        float4 va = *(const float4*)&fb[(size_t)(i0 + rr) * C + kc + c4 * 4];
        As[(c4 * 4 + 0) * P + sc] = va.x;
        As[(c4 * 4 + 1) * P + sc] = va.y;
        As[(c4 * 4 + 2) * P + sc] = va.z;
        As[(c4 * 4 + 3) * P + sc] = va.w;
        float4 vb = *(const float4*)&fb[(size_t)(j0 + rr) * C + kc + c4 * 4];
        Bs[(c4 * 4 + 0) * P + sc] = vb.x;
        Bs[(c4 * 4 + 1) * P + sc] = vb.y;
        Bs[(c4 * 4 + 2) * P + sc] = vb.z;
        Bs[(c4 * 4 + 3) * P + sc] = vb.w;
      }
      __syncthreads();
#pragma unroll 8
      for (int k = 0; k < BK; k++) {
        float4 a0 = *(const float4*)&As[k * P + aoff];
        float4 a1 = *(const float4*)&As[k * P + aoff + 4];
        float4 b0 = *(const float4*)&Bs[k * P + boff];
        float4 b1 = *(const float4*)&Bs[k * P + boff + 4];
        float av[8] = {a0.x, a0.y, a0.z, a0.w, a1.x, a1.y, a1.z, a1.w};
        float bv[8] = {b0.x, b0.y, b0.z, b0.w, b1.x, b1.y, b1.z, b1.w};
#pragma unroll
        for (int ii = 0; ii < 8; ii++)
#pragma unroll
          for (int jj = 0; jj < 8; jj++)
            acc[ii][jj] = fmaf(av[ii], bv[jj], acc[ii][jj]);
      }
    }

    if (tx < 8) {
      float4 q0 = *(const float4*)&sqB[tx * 8];
      float4 q1 = *(const float4*)&sqB[tx * 8 + 4];
#pragma unroll
      for (int ii = 0; ii < 8; ii++) {
        float4 o0 = make_float4(acc[ii][0] - q0.x, acc[ii][1] - q0.y,
                                acc[ii][2] - q0.z, acc[ii][3] - q0.w);
        float4 o1 = make_float4(acc[ii][4] - q1.x, acc[ii][5] - q1.y,
                                acc[ii][6] - q1.z, acc[ii][7] - q1.w);
        *(float4*)&Dt[(ty * 8 + ii) * 68 + tx * 8] = o0;
        *(float4*)&Dt[(ty * 8 + ii) * 68 + tx * 8 + 4] = o1;
      }
    }
    __syncthreads();
#pragma unroll
    for (int t4 = 0; t4 < 8; t4++) {
      float4 v = *(const float4*)&Dt[selr * 68 + sels * 32 + t4 * 4];
      int jb = j0 + sels * 32 + t4 * 4;
      pins16(pk(v.x, jb + 0), tv);
      pins16(pk(v.y, jb + 1), tv);
      pins16(pk(v.z, jb + 2), tv);
      pins16(pk(v.w, jb + 3), tv);
    }
    __syncthreads();
    if (tx >= 8) {
      float4 q0 = *(const float4*)&sqB[tx * 8];
      float4 q1 = *(const float4*)&sqB[tx * 8 + 4];
#pragma unroll
      for (int ii = 0; ii < 8; ii++) {
        float4 o0 = make_float4(acc[ii][0] - q0.x, acc[ii][1] - q0.y,
                                acc[ii][2] - q0.z, acc[ii][3] - q0.w);
        float4 o1 = make_float4(acc[ii][4] - q1.x, acc[ii][5] - q1.y,
                                acc[ii][6] - q1.z, acc[ii][7] - q1.w);
        *(float4*)&Dt[(ty * 8 + ii) * 68 + (tx - 8) * 8] = o0;
        *(float4*)&Dt[(ty * 8 + ii) * 68 + (tx - 8) * 8 + 4] = o1;
      }
    }
    __syncthreads();
#pragma unroll
    for (int t4 = 0; t4 < 8; t4++) {
      float4 v = *(const float4*)&Dt[selr * 68 + sels * 32 + t4 * 4];
      int jb = j0 + 64 + sels * 32 + t4 * 4;
      pins16(pk(v.x, jb + 0), tv);
      pins16(pk(v.y, jb + 1), tv);
      pins16(pk(v.z, jb + 2), tv);
      pins16(pk(v.w, jb + 3), tv);
    }
    __syncthreads();
  }

  int p = b * NTOT + i0 + selr;
  int sub = js * 2 + sels;
#pragma unroll
  for (int t = 0; t < KSUB; t++)
    cval[(size_t)(sub * KSUB + t) * (NBATCH * NTOT) + p] = tv[t];
}

// ---------------- merge + exact refine ----------------
template <int C>
__global__ __launch_bounds__(128) void kref_k(const float* __restrict__ feat,
                                              const unsigned* __restrict__ cval,
                                              int* __restrict__ outidx) {
  int p = blockIdx.x * 128 + threadIdx.x;
  int b = p >> 12;
  unsigned tv[KMRG];
#pragma unroll
  for (int t = 0; t < KMRG; t++) tv[t] = 0u;
#pragma unroll 2
  for (int t = 0; t < JSPLIT * 2 * KSUB; t++) {
    unsigned u = cval[(size_t)t * (NBATCH * NTOT) + p];
    if (u > tv[0]) {
      tv[0] = u;
#pragma unroll
      for (int x = 1; x < KMRG; x++) {
        unsigned mn = min(tv[0], tv[x]);
        unsigned mx = max(tv[0], tv[x]);
        tv[0] = mn;
        tv[x] = mx;
      }
    }
  }

  const float* fb = feat + (size_t)b * NTOT * C;
  const float* fi = fb + (size_t)(p & (NTOT - 1)) * C;
  float ev[KNN];
  int ej[KNN];
#pragma unroll
  for (int t = 0; t < KNN; t++) { ev[t] = NEG_INF; ej[t] = 0; }
  float minv = NEG_INF;
  int minp = 0;
#pragma unroll 1
  for (int u = 0; u < KMRG; u++) {
    int j = (int)(tv[u] & 0xFFFu);
    const float* fj = fb + (size_t)j * C;
    float a0 = 0.f, a1 = 0.f, a2 = 0.f, a3 = 0.f;
#pragma unroll 4
    for (int c4 = 0; c4 < C / 4; c4++) {
      float4 x = *(const float4*)&fi[c4 * 4];
      float4 y = *(const float4*)&fj[c4 * 4];
      float d0 = x.x - y.x, d1 = x.y - y.y, d2 = x.z - y.z, d3 = x.w - y.w;
      a0 = fmaf(d0, d0, a0);
      a1 = fmaf(d1, d1, a1);
      a2 = fmaf(d2, d2, a2);
      a3 = fmaf(d3, d3, a3);
    }
    topk_insert(-((a0 + a1) + (a2 + a3)), j, ev, ej, minv, minp);
  }
#pragma unroll
  for (int t = 0; t < KNN; t++) outidx[(size_t)p * KNN + t] = ej[t];
}

// ---------------- GEMM: Y[M x N2] = A[M x K] * Wc[N2 x K]^T (+bias) ----------
__global__ __launch_bounds__(256) void gemm_k(const float* __restrict__ A,
                                              const float* __restrict__ Wc,
                                              const float* __restrict__ bias,
                                              float* __restrict__ Y, int K, int N2,
                                              int O) {
  __shared__ float As[8 * 68];
  __shared__ float Bs[8 * 68];
  int tid = threadIdx.x;
  int n0 = blockIdx.x * 64;
  int m0 = blockIdx.y * 64;
  int tx = tid & 15, ty = tid >> 4;
  float acc[4][4] = {};
  for (int k0 = 0; k0 < K; k0 += 8) {
    __syncthreads();
    {
      int e = tid, mm = e >> 3, kk = e & 7;
      As[kk * 68 + mm] = (k0 + kk < K) ? A[(size_t)(m0 + mm) * K + k0 + kk] : 0.f;
      int nn = mm;
      Bs[kk * 68 + nn] = (k0 + kk < K) ? Wc[(size_t)(n0 + nn) * K + k0 + kk] : 0.f;
      e = tid + 256;
      mm = e >> 3;
      kk = e & 7;
      As[kk * 68 + mm] = (k0 + kk < K) ? A[(size_t)(m0 + mm) * K + k0 + kk] : 0.f;
      nn = mm;
      Bs[kk * 68 + nn] = (k0 + kk < K) ? Wc[(size_t)(n0 + nn) * K + k0 + kk] : 0.f;
    }
    __syncthreads();
#pragma unroll
    for (int kk = 0; kk < 8; kk++) {
      float4 av = *(float4*)&As[kk * 68 + ty * 4];
      float4 bv = *(float4*)&Bs[kk * 68 + tx * 4];
      float a[4] = {av.x, av.y, av.z, av.w};
      float bb2[4] = {bv.x, bv.y, bv.z, bv.w};
#pragma unroll
      for (int ii = 0; ii < 4; ii++)
#pragma unroll
        for (int jj = 0; jj < 4; jj++) acc[ii][jj] += a[ii] * bb2[jj];
    }
  }
  int col = n0 + tx * 4;
  bool isV = (col >= O);
  float b0 = 0.f, b1 = 0.f, b2 = 0.f, b3 = 0.f;
  if (isV) {
    b0 = bias[col + 0 - O];
    b1 = bias[col + 1 - O];
    b2 = bias[col + 2 - O];
    b3 = bias[col + 3 - O];
  }
#pragma unroll
  for (int ii = 0; ii < 4; ii++) {
    int row = m0 + ty * 4 + ii;
    float4 o4;
    o4.x = acc[ii][0] + b0;
    o4.y = acc[ii][1] + b1;
    o4.z = acc[ii][2] + b2;
    o4.w = acc[ii][3] + b3;
    *(float4*)&Y[(size_t)row * N2 + col] = o4;
  }
}

// ---------------- gather + max + LeakyReLU ----------------
__global__ void gmax_k(const float* __restrict__ Y, const int* __restrict__ idx,
                       float* __restrict__ out, int O) {
  int p = blockIdx.x;
  int o = threadIdx.x;
  int b = p >> 12;
  int N2 = 2 * O;
  const int* ip = idx + (size_t)p * KNN;
  float m = NEG_INF;
#pragma unroll
  for (int k = 0; k < KNN; k++) {
    int j = ip[k];
    m = fmaxf(m, Y[((size_t)(b * NTOT + j)) * N2 + o]);
  }
  float val = Y[(size_t)p * N2 + O + o] + m;
  out[(size_t)p * O + o] = (val >= 0.f) ? val : 0.2f * val;
}

// ---------------- host side ----------------
template <int C, int O>
static void run_layer(const float* fin, void* const* w5, float* fout, float* Wc,
                      float* biasb, int* idx, float* Y, float* sqh,
                      unsigned* cval, hipStream_t stream) {
  const float* W = (const float*)w5[0];
  const float* g = (const float*)w5[1];
  const float* bb = (const float*)w5[2];
  const float* mm = (const float*)w5[3];
  const float* vv = (const float*)w5[4];
  int N2 = 2 * O;
  prep_w<<<(2 * O * C + 255) / 256, 256, 0, stream>>>(W, g, bb, mm, vv, Wc, biasb, O, C);
  if (C == 3) {
    knn3_k<<<NBATCH * (NTOT / 32), 256, 0, stream>>>(fin, idx);
  } else {
    constexpr int CC = (C == 3) ? 64 : C;
    sqh_k<CC><<<NBATCH * NTOT / 256, 256, 0, stream>>>(fin, sqh);
    knn_g<CC><<<NBATCH * 32 * JSPLIT, 256, 0, stream>>>(fin, sqh, cval);
    kref_k<CC><<<NBATCH * NTOT / 128, 128, 0, stream>>>(fin, cval, idx);
  }
  dim3 gg(N2 / 64, NBATCH * NTOT / 64);
  gemm_k<<<gg, 256, 0, stream>>>(fin, Wc, biasb, Y, C, N2, O);
  gmax_k<<<NBATCH * NTOT, O, 0, stream>>>(Y, idx, fout, O);
}

extern "C" void kernel_launch(void* const* d_in, const int* in_sizes, int n_in,
                              void* d_out, int out_size, void* d_ws, size_t ws_size,
                              hipStream_t stream) {
  const float* x = (const float*)d_in[0];
  char* ws = (char*)d_ws;
  float* Wc = (float*)(ws + 0);            // 262144
  float* biasb = (float*)(ws + 262144);    // 1024
  int* idx = (int*)(ws + 263168);          // 1310720
  float* sqh = (float*)(ws + 1573888);     // 65536
  float* Y = (float*)(ws + 1639424);       // 33554432 -> ends 35193856
  float* x1 = (float*)(ws + 35193856);     // 4194304
  float* x2 = (float*)(ws + 39388160);     // 4194304
  float* x3 = (float*)(ws + 43582464);     // 8388608

  unsigned* cval = (unsigned*)Y;           // 128*16384*4 = 8.4 MB, consumed pre-gemm

  float* outf = (float*)d_out;

  run_layer<3, 64>(x, d_in + 1, x1, Wc, biasb, idx, Y, sqh, cval, stream);
  run_layer<64, 64>(x1, d_in + 6, x2, Wc, biasb, idx, Y, sqh, cval, stream);
  run_layer<64, 128>(x2, d_in + 11, x3, Wc, biasb, idx, Y, sqh, cval, stream);
  run_layer<128, 256>(x3, d_in + 16, outf, Wc, biasb, idx, Y, sqh, cval, stream);
}

// Round 6
// 1507.606 us; speedup vs baseline: 5.8557x; 1.1088x over previous
//
#include <hip/hip_runtime.h>

#define NTOT 4096
#define NBATCH 4
#define KNN 20
#define JSPLIT 4
#define KSUB 16
#define KMRG 28

constexpr float NEG_INF = -3.0e38f;

__device__ __forceinline__ unsigned pk(float f, int j) {
  unsigned u = __float_as_uint(f);
  u = (u & 0x80000000u) ? ~u : (u | 0x80000000u);
  return (u & 0xFFFFF000u) | (unsigned)j;
}

__device__ __forceinline__ void pins16(unsigned u, unsigned (&tv)[KSUB]) {
  if (u > tv[0]) {
    tv[0] = u;
#pragma unroll
    for (int x = 1; x < KSUB; x++) {
      unsigned mn = min(tv[0], tv[x]);
      unsigned mx = max(tv[0], tv[x]);
      tv[0] = mn;
      tv[x] = mx;
    }
  }
}

__device__ __forceinline__ void topk_insert(float val, int j, float (&tv)[KNN],
                                            int (&tj)[KNN], float& minv, int& minp) {
  if (val > minv) {
#pragma unroll
    for (int u = 0; u < KNN; u++) {
      bool w = (minp == u);
      tv[u] = w ? val : tv[u];
      tj[u] = w ? j : tj[u];
    }
    minv = tv[0];
    minp = 0;
#pragma unroll
    for (int u = 1; u < KNN; u++)
      if (tv[u] < minv) { minv = tv[u]; minp = u; }
  }
}

// ---------------- prep: fold BN scale into weights ----------------
__global__ void prep_w(const float* __restrict__ W, const float* __restrict__ gg,
                       const float* __restrict__ bb, const float* __restrict__ mm,
                       const float* __restrict__ vv, float* __restrict__ Wc,
                       float* __restrict__ bias, int O, int C) {
  int t = blockIdx.x * 256 + threadIdx.x;
  if (t >= 2 * O * C) return;
  int o2 = t / C, c = t - o2 * C;
  int o = (o2 < O) ? o2 : o2 - O;
  float s = gg[o] * rsqrtf(vv[o] + 1e-5f);
  float w = (o2 < O) ? W[o * 2 * C + c] * s
                     : (W[o * 2 * C + C + c] - W[o * 2 * C + c]) * s;
  Wc[o2 * C + c] = w;
  if (o2 >= O && c == 0) bias[o] = bb[o] - mm[o] * s;
}

// ---------------- half squared norms ----------------
template <int C>
__global__ void sqh_k(const float* __restrict__ f, float* __restrict__ sqh) {
  int p = blockIdx.x * 256 + threadIdx.x;
  const float* r = f + (size_t)p * C;
  float s = 0.f;
#pragma unroll
  for (int c4 = 0; c4 < C / 4; c4++) {
    float4 v = *(const float4*)&r[c4 * 4];
    s += v.x * v.x + v.y * v.y + v.z * v.z + v.w * v.w;
  }
  sqh[p] = 0.5f * s;
}

// ---------------- KNN C=3 stage 1: packed top-16, 4 sub-lists/row ----------
__global__ __launch_bounds__(256) void knn3_g(const float* __restrict__ feat,
                                              unsigned* __restrict__ cval) {
  __shared__ __align__(16) float sA[64 * 4];

  int tid = threadIdx.x;
  int rb = blockIdx.x & 63;   // 4096/64 = 64 row-blocks per batch
  int b = blockIdx.x >> 6;
  int row0 = rb * 64;
  int r = tid >> 2, q = tid & 3;  // 64 rows x 4 threads/row
  int i = row0 + r;
  const float* fb = feat + (size_t)b * NTOT * 3;

  float c0 = fb[(size_t)i * 3 + 0];
  float c1 = fb[(size_t)i * 3 + 1];
  float c2 = fb[(size_t)i * 3 + 2];

  unsigned tv[KSUB];
#pragma unroll
  for (int t = 0; t < KSUB; t++) tv[t] = 0u;

  for (int jt = 0; jt < NTOT; jt += 64) {
    __syncthreads();
    if (tid < 64) {
      sA[tid * 4 + 0] = fb[(size_t)(jt + tid) * 3 + 0];
      sA[tid * 4 + 1] = fb[(size_t)(jt + tid) * 3 + 1];
      sA[tid * 4 + 2] = fb[(size_t)(jt + tid) * 3 + 2];
    }
    __syncthreads();

#pragma unroll
    for (int cc = 0; cc < 16; cc++) {
      int jl = cc * 4 + q;
      float d0 = c0 - sA[jl * 4];
      float d1 = c1 - sA[jl * 4 + 1];
      float d2 = c2 - sA[jl * 4 + 2];
      float val = -(d0 * d0 + d1 * d1 + d2 * d2);
      pins16(pk(val, jt + jl), tv);
    }
  }

  int p = b * NTOT + row0 + r;
#pragma unroll
  for (int t = 0; t < KSUB; t++)
    cval[(size_t)(q * KSUB + t) * (NBATCH * NTOT) + p] = tv[t];
}

// ---------------- KNN stage 1 (C=64/128): dot-form + packed top-16 ----------
template <int C>
__global__ __launch_bounds__(256, 2) void knn_g(const float* __restrict__ feat,
                                                const float* __restrict__ sqh,
                                                unsigned* __restrict__ cval) {
  constexpr int P = 140;
  constexpr int BK = 32;
  __shared__ float As[BK * P];
  __shared__ float Bs[BK * P];
  __shared__ float Dt[128 * 68];
  __shared__ float sqB[128];

  int tid = threadIdx.x;
  int js = blockIdx.x & (JSPLIT - 1);
  int it = (blockIdx.x >> 2) & 31;
  int b = blockIdx.x >> 7;
  int i0 = it * 128;
  const float* fb = feat + (size_t)b * NTOT * C;

  int tx = tid & 15, ty = tid >> 4;
  int aoff = (ty * 8) + (((ty * 8) >> 5) << 2);
  int boff = (tx * 8) + (((tx * 8) >> 5) << 2);
  int selr = tid >> 1;
  int sels = tid & 1;

  unsigned tv[KSUB];
#pragma unroll
  for (int t = 0; t < KSUB; t++) tv[t] = 0u;

  for (int jt = 0; jt < NTOT / (128 * JSPLIT); jt++) {
    int j0 = js * (NTOT / JSPLIT) + jt * 128;
    if (tid < 128) sqB[tid] = sqh[b * NTOT + j0 + tid];

    float acc[8][8];
#pragma unroll
    for (int ii = 0; ii < 8; ii++)
#pragma unroll
      for (int jj = 0; jj < 8; jj++) acc[ii][jj] = 0.f;

    for (int kc = 0; kc < C; kc += BK) {
      __syncthreads();
#pragma unroll
      for (int l = 0; l < 4; l++) {
        int e = tid + 256 * l;
        int rr = e >> 3, c4 = e & 7;
        int sc = rr + ((rr >> 5) << 2);
        float4 va = *(const float4*)&fb[(size_t)(i0 + rr) * C + kc + c4 * 4];
        As[(c4 * 4 + 0) * P + sc] = va.x;
        As[(c4 * 4 + 1) * P + sc] = va.y;
        As[(c4 * 4 + 2) * P + sc] = va.z;
        As[(c4 * 4 + 3) * P + sc] = va.w;
        float4 vb = *(const float4*)&fb[(size_t)(j0 + rr) * C + kc + c4 * 4];
        Bs[(c4 * 4 + 0) * P + sc] = vb.x;
        Bs[(c4 * 4 + 1) * P + sc] = vb.y;
        Bs[(c4 * 4 + 2) * P + sc] = vb.z;
        Bs[(c4 * 4 + 3) * P + sc] = vb.w;
      }
      __syncthreads();
#pragma unroll 8
      for (int k = 0; k < BK; k++) {
        float4 a0 = *(const float4*)&As[k * P + aoff];
        float4 a1 = *(const float4*)&As[k * P + aoff + 4];
        float4 b0 = *(const float4*)&Bs[k * P + boff];
        float4 b1 = *(const float4*)&Bs[k * P + boff + 4];
        float av[8] = {a0.x, a0.y, a0.z, a0.w, a1.x, a1.y, a1.z, a1.w};
        float bv[8] = {b0.x, b0.y, b0.z, b0.w, b1.x, b1.y, b1.z, b1.w};
#pragma unroll
        for (int ii = 0; ii < 8; ii++)
#pragma unroll
          for (int jj = 0; jj < 8; jj++)
            acc[ii][jj] = fmaf(av[ii], bv[jj], acc[ii][jj]);
      }
    }

    if (tx < 8) {
      float4 q0 = *(const float4*)&sqB[tx * 8];
      float4 q1 = *(const float4*)&sqB[tx * 8 + 4];
#pragma unroll
      for (int ii = 0; ii < 8; ii++) {
        float4 o0 = make_float4(acc[ii][0] - q0.x, acc[ii][1] - q0.y,
                                acc[ii][2] - q0.z, acc[ii][3] - q0.w);
        float4 o1 = make_float4(acc[ii][4] - q1.x, acc[ii][5] - q1.y,
                                acc[ii][6] - q1.z, acc[ii][7] - q1.w);
        *(float4*)&Dt[(ty * 8 + ii) * 68 + tx * 8] = o0;
        *(float4*)&Dt[(ty * 8 + ii) * 68 + tx * 8 + 4] = o1;
      }
    }
    __syncthreads();
#pragma unroll
    for (int t4 = 0; t4 < 8; t4++) {
      float4 v = *(const float4*)&Dt[selr * 68 + sels * 32 + t4 * 4];
      int jb = j0 + sels * 32 + t4 * 4;
      pins16(pk(v.x, jb + 0), tv);
      pins16(pk(v.y, jb + 1), tv);
      pins16(pk(v.z, jb + 2), tv);
      pins16(pk(v.w, jb + 3), tv);
    }
    __syncthreads();
    if (tx >= 8) {
      float4 q0 = *(const float4*)&sqB[tx * 8];
      float4 q1 = *(const float4*)&sqB[tx * 8 + 4];
#pragma unroll
      for (int ii = 0; ii < 8; ii++) {
        float4 o0 = make_float4(acc[ii][0] - q0.x, acc[ii][1] - q0.y,
                                acc[ii][2] - q0.z, acc[ii][3] - q0.w);
        float4 o1 = make_float4(acc[ii][4] - q1.x, acc[ii][5] - q1.y,
                                acc[ii][6] - q1.z, acc[ii][7] - q1.w);
        *(float4*)&Dt[(ty * 8 + ii) * 68 + (tx - 8) * 8] = o0;
        *(float4*)&Dt[(ty * 8 + ii) * 68 + (tx - 8) * 8 + 4] = o1;
      }
    }
    __syncthreads();
#pragma unroll
    for (int t4 = 0; t4 < 8; t4++) {
      float4 v = *(const float4*)&Dt[selr * 68 + sels * 32 + t4 * 4];
      int jb = j0 + 64 + sels * 32 + t4 * 4;
      pins16(pk(v.x, jb + 0), tv);
      pins16(pk(v.y, jb + 1), tv);
      pins16(pk(v.z, jb + 2), tv);
      pins16(pk(v.w, jb + 3), tv);
    }
    __syncthreads();
  }

  int p = b * NTOT + i0 + selr;
  int sub = js * 2 + sels;
#pragma unroll
  for (int t = 0; t < KSUB; t++)
    cval[(size_t)(sub * KSUB + t) * (NBATCH * NTOT) + p] = tv[t];
}

// ---------------- merge + exact refine ----------------
template <int C, int NSUB>
__global__ __launch_bounds__(128) void kref_k(const float* __restrict__ feat,
                                              const unsigned* __restrict__ cval,
                                              int* __restrict__ outidx) {
  int p = blockIdx.x * 128 + threadIdx.x;
  int b = p >> 12;
  unsigned tv[KMRG];
#pragma unroll
  for (int t = 0; t < KMRG; t++) tv[t] = 0u;
#pragma unroll 2
  for (int t = 0; t < NSUB * KSUB; t++) {
    unsigned u = cval[(size_t)t * (NBATCH * NTOT) + p];
    if (u > tv[0]) {
      tv[0] = u;
#pragma unroll
      for (int x = 1; x < KMRG; x++) {
        unsigned mn = min(tv[0], tv[x]);
        unsigned mx = max(tv[0], tv[x]);
        tv[0] = mn;
        tv[x] = mx;
      }
    }
  }

  const float* fb = feat + (size_t)b * NTOT * C;
  const float* fi = fb + (size_t)(p & (NTOT - 1)) * C;
  float ev[KNN];
  int ej[KNN];
#pragma unroll
  for (int t = 0; t < KNN; t++) { ev[t] = NEG_INF; ej[t] = 0; }
  float minv = NEG_INF;
  int minp = 0;
#pragma unroll 1
  for (int u = 0; u < KMRG; u++) {
    int j = (int)(tv[u] & 0xFFFu);
    const float* fj = fb + (size_t)j * C;
    float val;
    if (C == 3) {
      float d0 = fi[0] - fj[0];
      float d1 = fi[1] - fj[1];
      float d2 = fi[2] - fj[2];
      val = -(d0 * d0 + d1 * d1 + d2 * d2);
    } else {
      float a0 = 0.f, a1 = 0.f, a2 = 0.f, a3 = 0.f;
#pragma unroll 4
      for (int c4 = 0; c4 < C / 4; c4++) {
        float4 x = *(const float4*)&fi[c4 * 4];
        float4 y = *(const float4*)&fj[c4 * 4];
        float d0 = x.x - y.x, d1 = x.y - y.y, d2 = x.z - y.z, d3 = x.w - y.w;
        a0 = fmaf(d0, d0, a0);
        a1 = fmaf(d1, d1, a1);
        a2 = fmaf(d2, d2, a2);
        a3 = fmaf(d3, d3, a3);
      }
      val = -((a0 + a1) + (a2 + a3));
    }
    topk_insert(val, j, ev, ej, minv, minp);
  }
#pragma unroll
  for (int t = 0; t < KNN; t++) outidx[(size_t)p * KNN + t] = ej[t];
}

// ---------------- GEMM: Y[M x N2] = A[M x K] * Wc[N2 x K]^T (+bias) ----------
__global__ __launch_bounds__(256) void gemm_k(const float* __restrict__ A,
                                              const float* __restrict__ Wc,
                                              const float* __restrict__ bias,
                                              float* __restrict__ Y, int K, int N2,
                                              int O) {
  __shared__ float As[8 * 68];
  __shared__ float Bs[8 * 68];
  int tid = threadIdx.x;
  int n0 = blockIdx.x * 64;
  int m0 = blockIdx.y * 64;
  int tx = tid & 15, ty = tid >> 4;
  float acc[4][4] = {};
  for (int k0 = 0; k0 < K; k0 += 8) {
    __syncthreads();
    {
      int e = tid, mm = e >> 3, kk = e & 7;
      As[kk * 68 + mm] = (k0 + kk < K) ? A[(size_t)(m0 + mm) * K + k0 + kk] : 0.f;
      int nn = mm;
      Bs[kk * 68 + nn] = (k0 + kk < K) ? Wc[(size_t)(n0 + nn) * K + k0 + kk] : 0.f;
      e = tid + 256;
      mm = e >> 3;
      kk = e & 7;
      As[kk * 68 + mm] = (k0 + kk < K) ? A[(size_t)(m0 + mm) * K + k0 + kk] : 0.f;
      nn = mm;
      Bs[kk * 68 + nn] = (k0 + kk < K) ? Wc[(size_t)(n0 + nn) * K + k0 + kk] : 0.f;
    }
    __syncthreads();
#pragma unroll
    for (int kk = 0; kk < 8; kk++) {
      float4 av = *(float4*)&As[kk * 68 + ty * 4];
      float4 bv = *(float4*)&Bs[kk * 68 + tx * 4];
      float a[4] = {av.x, av.y, av.z, av.w};
      float bb2[4] = {bv.x, bv.y, bv.z, bv.w};
#pragma unroll
      for (int ii = 0; ii < 4; ii++)
#pragma unroll
        for (int jj = 0; jj < 4; jj++) acc[ii][jj] += a[ii] * bb2[jj];
    }
  }
  int col = n0 + tx * 4;
  bool isV = (col >= O);
  float b0 = 0.f, b1 = 0.f, b2 = 0.f, b3 = 0.f;
  if (isV) {
    b0 = bias[col + 0 - O];
    b1 = bias[col + 1 - O];
    b2 = bias[col + 2 - O];
    b3 = bias[col + 3 - O];
  }
#pragma unroll
  for (int ii = 0; ii < 4; ii++) {
    int row = m0 + ty * 4 + ii;
    float4 o4;
    o4.x = acc[ii][0] + b0;
    o4.y = acc[ii][1] + b1;
    o4.z = acc[ii][2] + b2;
    o4.w = acc[ii][3] + b3;
    *(float4*)&Y[(size_t)row * N2 + col] = o4;
  }
}

// ---------------- gather + max + LeakyReLU ----------------
__global__ void gmax_k(const float* __restrict__ Y, const int* __restrict__ idx,
                       float* __restrict__ out, int O) {
  int p = blockIdx.x;
  int o = threadIdx.x;
  int b = p >> 12;
  int N2 = 2 * O;
  const int* ip = idx + (size_t)p * KNN;
  float m = NEG_INF;
#pragma unroll
  for (int k = 0; k < KNN; k++) {
    int j = ip[k];
    m = fmaxf(m, Y[((size_t)(b * NTOT + j)) * N2 + o]);
  }
  float val = Y[(size_t)p * N2 + O + o] + m;
  out[(size_t)p * O + o] = (val >= 0.f) ? val : 0.2f * val;
}

// ---------------- host side ----------------
template <int C, int O>
static void run_layer(const float* fin, void* const* w5, float* fout, float* Wc,
                      float* biasb, int* idx, float* Y, float* sqh,
                      unsigned* cval, hipStream_t stream) {
  const float* W = (const float*)w5[0];
  const float* g = (const float*)w5[1];
  const float* bb = (const float*)w5[2];
  const float* mm = (const float*)w5[3];
  const float* vv = (const float*)w5[4];
  int N2 = 2 * O;
  prep_w<<<(2 * O * C + 255) / 256, 256, 0, stream>>>(W, g, bb, mm, vv, Wc, biasb, O, C);
  if (C == 3) {
    knn3_g<<<NBATCH * (NTOT / 64), 256, 0, stream>>>(fin, cval);
    kref_k<3, 4><<<NBATCH * NTOT / 128, 128, 0, stream>>>(fin, cval, idx);
  } else {
    constexpr int CC = (C == 3) ? 64 : C;
    sqh_k<CC><<<NBATCH * NTOT / 256, 256, 0, stream>>>(fin, sqh);
    knn_g<CC><<<NBATCH * 32 * JSPLIT, 256, 0, stream>>>(fin, sqh, cval);
    kref_k<CC, JSPLIT * 2><<<NBATCH * NTOT / 128, 128, 0, stream>>>(fin, cval, idx);
  }
  dim3 gg(N2 / 64, NBATCH * NTOT / 64);
  gemm_k<<<gg, 256, 0, stream>>>(fin, Wc, biasb, Y, C, N2, O);
  gmax_k<<<NBATCH * NTOT, O, 0, stream>>>(Y, idx, fout, O);
}

extern "C" void kernel_launch(void* const* d_in, const int* in_sizes, int n_in,
                              void* d_out, int out_size, void* d_ws, size_t ws_size,
                              hipStream_t stream) {
  const float* x = (const float*)d_in[0];
  char* ws = (char*)d_ws;
  float* Wc = (float*)(ws + 0);            // 262144
  float* biasb = (float*)(ws + 262144);    // 1024
  int* idx = (int*)(ws + 263168);          // 1310720
  float* sqh = (float*)(ws + 1573888);     // 65536
  float* Y = (float*)(ws + 1639424);       // 33554432 -> ends 35193856
  float* x1 = (float*)(ws + 35193856);     // 4194304
  float* x2 = (float*)(ws + 39388160);     // 4194304
  float* x3 = (float*)(ws + 43582464);     // 8388608

  unsigned* cval = (unsigned*)Y;           // <=8.4 MB, consumed before gemm_k

  float* outf = (float*)d_out;

  run_layer<3, 64>(x, d_in + 1, x1, Wc, biasb, idx, Y, sqh, cval, stream);
  run_layer<64, 64>(x1, d_in + 6, x2, Wc, biasb, idx, Y, sqh, cval, stream);
  run_layer<64, 128>(x2, d_in + 11, x3, Wc, biasb, idx, Y, sqh, cval, stream);
  run_layer<128, 256>(x3, d_in + 16, outf, Wc, biasb, idx, Y, sqh, cval, stream);
}